// Round 1
// baseline (45927.936 us; speedup 1.0000x reference)
//
#include <hip/hip_runtime.h>
#include <stdint.h>

#define B_ 64
#define S_ 1024
#define I_ 512
#define H_ 2048
#define O_ 512

typedef unsigned short u16;
typedef __attribute__((ext_vector_type(8))) short s8v;
typedef __attribute__((ext_vector_type(4))) float f4v;
typedef __attribute__((ext_vector_type(16))) float f16v;

__device__ __forceinline__ u16 f2bf(float f) {
  union { float f; unsigned u; } v; v.f = f;
  unsigned r = v.u + 0x7fffu + ((v.u >> 16) & 1u);
  return (u16)(r >> 16);
}

__device__ __forceinline__ void load_lds16(const void* g, void* l) {
  __builtin_amdgcn_global_load_lds(
      (const __attribute__((address_space(1))) void*)g,
      (__attribute__((address_space(3))) void*)l,
      16, 0, 0);
}

// ---------------------------------------------------------------------------
// prep: bf16 conversions, W_hh fragment packing, sigma(h0) -> slot 0, ctr=0
// ---------------------------------------------------------------------------
__global__ __launch_bounds__(256) void prep_kernel(
    const float* __restrict__ x, const float* __restrict__ h0,
    const float* __restrict__ Wih, const float* __restrict__ Whh,
    const float* __restrict__ Who,
    u16* __restrict__ xb, u16* __restrict__ wihb, u16* __restrict__ whhp,
    u16* __restrict__ whob, u16* __restrict__ sig, unsigned* __restrict__ ctr)
{
  const size_t tid = (size_t)blockIdx.x * blockDim.x + threadIdx.x;
  const size_t stride = (size_t)gridDim.x * blockDim.x;
  if (tid == 0) *ctr = 0u;

  for (size_t i = tid * 4; i < (size_t)B_ * S_ * I_; i += stride * 4) {
    float4 v = *(const float4*)(x + i);
    *(ushort4*)(xb + i) = make_ushort4(f2bf(v.x), f2bf(v.y), f2bf(v.z), f2bf(v.w));
  }
  for (size_t i = tid * 4; i < (size_t)H_ * I_; i += stride * 4) {
    float4 v = *(const float4*)(Wih + i);
    *(ushort4*)(wihb + i) = make_ushort4(f2bf(v.x), f2bf(v.y), f2bf(v.z), f2bf(v.w));
  }
  for (size_t i = tid * 4; i < (size_t)O_ * H_; i += stride * 4) {
    float4 v = *(const float4*)(Who + i);
    *(ushort4*)(whob + i) = make_ushort4(f2bf(v.x), f2bf(v.y), f2bf(v.z), f2bf(v.w));
  }
  // pack W_hh into per-WG fragment order:
  // p = wg*65536 + kappa*512 + lane*8 + e  holds Whh[n][k],
  // n = wg*32 + (lane&31), k = kappa*16 + (lane>>5)*8 + e
  for (size_t p = tid; p < (size_t)H_ * H_; p += stride) {
    unsigned pw = (unsigned)p;
    int wg = pw >> 16;
    int ka = (pw >> 9) & 127;
    int l  = (pw >> 3) & 63;
    int e  = pw & 7;
    int n = (wg << 5) | (l & 31);
    int k = (ka << 4) | ((l >> 5) << 3) | e;
    whhp[p] = f2bf(Whh[(size_t)n * H_ + k]);
  }
  for (size_t i = tid; i < (size_t)B_ * H_; i += stride) {
    float v = h0[i];
    sig[i] = f2bf(1.0f / (1.0f + __expf(-v)));
  }
}

// ---------------------------------------------------------------------------
// gemm_bt: C[M,N] = A[M,K](bf16) * B[N,K](bf16)^T (+bias), fp32 out
// 128x128 tile, BK=64, global_load_lds staging with XOR swizzle,
// 16x16x32 bf16 MFMA, 2x2 waves each 64x64.
// cmode 0: C row-major ld=N.  cmode 1: row m=(s*64+b) -> C[b*S*O + s*O + col]
// ---------------------------------------------------------------------------
__global__ __launch_bounds__(256) void gemm_bt(
    const u16* __restrict__ A, const u16* __restrict__ Bm,
    float* __restrict__ C, const float* __restrict__ bias,
    int M, int N, int K, int cmode)
{
  __shared__ u16 lA[128 * 64];
  __shared__ u16 lB[128 * 64];
  const int tid = threadIdx.x;
  const int wave = tid >> 6, lane = tid & 63;
  const int nwgN = N >> 7;
  const int M0 = (blockIdx.x / nwgN) << 7;
  const int N0 = (blockIdx.x % nwgN) << 7;
  const int wm = wave >> 1, wn = wave & 1;
  const int lr = lane & 15, lg = lane >> 4;
  const int swz = lane & 7;

  f4v acc[4][4];
#pragma unroll
  for (int a = 0; a < 4; ++a)
#pragma unroll
    for (int b = 0; b < 4; ++b)
#pragma unroll
      for (int r = 0; r < 4; ++r) acc[a][b][r] = 0.0f;

  for (int kc = 0; kc < K; kc += 64) {
    __syncthreads();
#pragma unroll
    for (int i = 0; i < 4; ++i) {
      int E = (i * 256 + tid) * 8;     // linear bf16 element index in tile
      int row = E >> 6;                // 0..127
      int gl = (E >> 3) & 7;           // LDS k-group slot
      int gs = gl ^ (row & 7);         // swizzled source k-group
      load_lds16(A + (size_t)(M0 + row) * K + kc + (gs << 3),
                 &lA[(i * 256 + wave * 64) * 8]);
      load_lds16(Bm + (size_t)(N0 + row) * K + kc + (gs << 3),
                 &lB[(i * 256 + wave * 64) * 8]);
    }
    __syncthreads();
#pragma unroll
    for (int ki = 0; ki < 2; ++ki) {
      s8v af[4], bfr[4];
#pragma unroll
      for (int mt = 0; mt < 4; ++mt) {
        int r = wm * 64 + mt * 16 + lr;
        int slot = (ki * 4 + lg) ^ swz;
        af[mt] = *(const s8v*)&lA[r * 64 + slot * 8];
      }
#pragma unroll
      for (int nt = 0; nt < 4; ++nt) {
        int r = wn * 64 + nt * 16 + lr;
        int slot = (ki * 4 + lg) ^ swz;
        bfr[nt] = *(const s8v*)&lB[r * 64 + slot * 8];
      }
#pragma unroll
      for (int mt = 0; mt < 4; ++mt)
#pragma unroll
        for (int nt = 0; nt < 4; ++nt)
          acc[mt][nt] = __builtin_amdgcn_mfma_f32_16x16x32_bf16(
              af[mt], bfr[nt], acc[mt][nt], 0, 0, 0);
    }
  }

#pragma unroll
  for (int nt = 0; nt < 4; ++nt) {
    int col = N0 + wn * 64 + nt * 16 + lr;
    float bv = bias ? bias[col] : 0.0f;
#pragma unroll
    for (int mt = 0; mt < 4; ++mt) {
      int rowb = M0 + wm * 64 + mt * 16 + lg * 4;
#pragma unroll
      for (int r = 0; r < 4; ++r) {
        int rr = rowb + r;
        size_t off = cmode
            ? ((size_t)(rr & 63) * ((size_t)S_ * O_) + (size_t)(rr >> 6) * O_ + col)
            : ((size_t)rr * (size_t)N + col);
        C[off] = acc[mt][nt][r] + bv;
      }
    }
  }
}

// ---------------------------------------------------------------------------
// recur: persistent recurrence. 64 WGs x 64 threads. WG wg owns hidden cols
// [wg*32, wg*32+32). Wave tile: 2 Mt (batches 0-31 / 32-63) x 1 Nt(32),
// full K=2048, 32x32x16 bf16 MFMA, 4 independent acc chains.
// h kept in registers (C-layout). sigma(h_t) published to slot t+1 (bf16).
// hidden region doubles as xw input (read (b,t) then overwritten).
// Device barrier: monotonic agent-scope atomic counter.
// ---------------------------------------------------------------------------
__global__ __launch_bounds__(64) void recur_kernel(
    const u16* __restrict__ whhp, const float* __restrict__ noise,
    const float* __restrict__ h0,
    float* __restrict__ hidden, u16* __restrict__ sig,
    unsigned* __restrict__ ctr)
{
  const int wg = blockIdx.x;      // 0..63
  const int lane = threadIdx.x;   // 0..63
  const int l31 = lane & 31, lq = lane >> 5;
  const int nc = wg << 5;
  const int j = nc + l31;         // output column (C-layout col = lane&31)

  int rowv[16];
  float hA[16], hB[16];
#pragma unroll
  for (int r = 0; r < 16; ++r) {
    int row = (r & 3) + ((r >> 2) << 3) + (lq << 2);  // C-layout row
    rowv[r] = row;
    hA[r] = h0[(size_t)row * H_ + j];
    hB[r] = h0[(size_t)(row + 32) * H_ + j];
  }

  const u16* bbase = whhp + ((size_t)wg << 16) + ((size_t)lane << 3);

  for (int t = 0; t < S_; ++t) {
    // prefetch xw and noise for this step (independent of MFMA loop)
    float xwA[16], xwB[16], nzA[16], nzB[16];
#pragma unroll
    for (int r = 0; r < 16; ++r) {
      int row = rowv[r];
      size_t hx = (size_t)row * ((size_t)S_ * H_) + (size_t)t * H_ + j;
      size_t nx = (size_t)t * ((size_t)B_ * H_) + (size_t)row * H_ + j;
      xwA[r] = hidden[hx];
      nzA[r] = noise[nx];
      xwB[r] = hidden[hx + (size_t)32 * S_ * H_];
      nzB[r] = noise[nx + (size_t)32 * H_];
    }

    const u16* aB0 = sig + (size_t)t * (B_ * H_) + (size_t)l31 * H_ + (lq << 3);
    const u16* aB1 = aB0 + (size_t)32 * H_;

    f16v acc0e, acc0o, acc1e, acc1o;
#pragma unroll
    for (int i = 0; i < 16; ++i) { acc0e[i] = 0.f; acc0o[i] = 0.f; acc1e[i] = 0.f; acc1o[i] = 0.f; }

#pragma unroll 4
    for (int k = 0; k < 128; k += 2) {
      s8v be  = *(const s8v*)(bbase + ((size_t)k << 9));
      s8v bo  = *(const s8v*)(bbase + ((size_t)(k + 1) << 9));
      s8v a0e = *(const s8v*)(aB0 + ((size_t)k << 4));
      s8v a0o = *(const s8v*)(aB0 + ((size_t)(k + 1) << 4));
      s8v a1e = *(const s8v*)(aB1 + ((size_t)k << 4));
      s8v a1o = *(const s8v*)(aB1 + ((size_t)(k + 1) << 4));
      acc0e = __builtin_amdgcn_mfma_f32_32x32x16_bf16(a0e, be, acc0e, 0, 0, 0);
      acc1e = __builtin_amdgcn_mfma_f32_32x32x16_bf16(a1e, be, acc1e, 0, 0, 0);
      acc0o = __builtin_amdgcn_mfma_f32_32x32x16_bf16(a0o, bo, acc0o, 0, 0, 0);
      acc1o = __builtin_amdgcn_mfma_f32_32x32x16_bf16(a1o, bo, acc1o, 0, 0, 0);
    }

    u16* sOut = sig + (size_t)(t + 1) * (B_ * H_);
#pragma unroll
    for (int r = 0; r < 16; ++r) {
      int row = rowv[r];
      size_t hx = (size_t)row * ((size_t)S_ * H_) + (size_t)t * H_ + j;
      float c0 = acc0e[r] + acc0o[r];
      float hn0 = 0.9f * hA[r] + 0.1f * (c0 + xwA[r]) + 0.01f * nzA[r];
      hA[r] = hn0;
      hidden[hx] = hn0;
      sOut[(size_t)row * H_ + j] = f2bf(1.0f / (1.0f + __expf(-hn0)));

      size_t hx2 = hx + (size_t)32 * S_ * H_;
      float c1 = acc1e[r] + acc1o[r];
      float hn1 = 0.9f * hB[r] + 0.1f * (c1 + xwB[r]) + 0.01f * nzB[r];
      hB[r] = hn1;
      hidden[hx2] = hn1;
      sOut[(size_t)(row + 32) * H_ + j] = f2bf(1.0f / (1.0f + __expf(-hn1)));
    }

    // device-wide barrier (monotonic counter, agent scope)
    if (lane == 0) {
      __threadfence();  // release: make our stores visible device-wide
      __hip_atomic_fetch_add(ctr, 1u, __ATOMIC_RELEASE, __HIP_MEMORY_SCOPE_AGENT);
      const unsigned tgt = (unsigned)(t + 1) * 64u;
      while (__hip_atomic_load(ctr, __ATOMIC_ACQUIRE, __HIP_MEMORY_SCOPE_AGENT) < tgt) {
        __builtin_amdgcn_s_sleep(2);
      }
      __threadfence();  // acquire: invalidate stale cache lines
    }
    __syncthreads();
  }
}

// ---------------------------------------------------------------------------
// launcher
// ---------------------------------------------------------------------------
extern "C" void kernel_launch(void* const* d_in, const int* in_sizes, int n_in,
                              void* d_out, int out_size, void* d_ws, size_t ws_size,
                              hipStream_t stream) {
  const float* x   = (const float*)d_in[0];
  const float* h0  = (const float*)d_in[1];
  const float* Wih = (const float*)d_in[2];
  const float* Whh = (const float*)d_in[3];
  const float* Who = (const float*)d_in[4];
  const float* bho = (const float*)d_in[5];
  const float* nz  = (const float*)d_in[6];

  float* out    = (float*)d_out;
  float* hidden = out + (size_t)B_ * S_ * O_;   // also holds xw until step t

  char* ws = (char*)d_ws;
  unsigned* ctr = (unsigned*)ws;                 // 512 B reserved
  u16* whhp = (u16*)(ws + 512);                  // 8388608 B
  u16* wihb = (u16*)(ws + 8389120);              // 2097152 B
  u16* whob = (u16*)(ws + 10486272);             // 2097152 B
  u16* xb   = (u16*)(ws + 12583424);             // 67108864 B
  u16* sig  = (u16*)(ws + 79692288);             // 1025*64*2048*2 B

  prep_kernel<<<2048, 256, 0, stream>>>(x, h0, Wih, Whh, Who,
                                        xb, wihb, whhp, whob, sig, ctr);
  // xw = x @ Wih^T  -> hidden region (fp32)
  gemm_bt<<<8192, 256, 0, stream>>>(xb, wihb, hidden, nullptr,
                                    65536, 2048, 512, 0);
  // recurrence (writes hidden fp32 + sigma slots 1..S)
  recur_kernel<<<64, 64, 0, stream>>>(whhp, nz, h0, hidden, sig, ctr);
  // out = sigma(hidden) @ Who^T + b  (A rows are [s][b] order -> cmode 1)
  gemm_bt<<<2048, 256, 0, stream>>>(sig + (size_t)B_ * H_, whob, out, bho,
                                    65536, 512, 2048, 1);
}